// Round 4
// baseline (199.320 us; speedup 1.0000x reference)
//
#include <hip/hip_runtime.h>
#include <hip/hip_bf16.h>

// Depthwise 4x4 binomial blur + stride-2 downsample, separable [1,3,3,1] x2, /64.
// Input (B*C, 256, 256) fp32 -> output (B*C, 128, 128) fp32, pad=1.
//
// Barrier-free, LDS-free. One wave produces FOUR output rows (4q..4q+3),
// reading the 10 input rows 8q-1..8q+8. Each input row is one wave-wide
// float4 load (64 lanes x 16 B = whole 256-float row) -> 10 independent
// dwordx4 loads in flight per wave. Horizontal [1,3,3,1] taps via 2 lane
// shuffles per row; vertical combine in registers; 4 x float2 row stores.
// Wave-level read amplification 10/8 = 1.25x; block-boundary halo 2/34 = 6%.

#define IN_H 256
#define IN_W 256
#define OUT_H 128
#define OUT_W 128

__global__ __launch_bounds__(256) void downsample_kernel(
    const float* __restrict__ x, float* __restrict__ y) {
    const int plane = blockIdx.y;
    const int q     = blockIdx.x * 4 + (threadIdx.x >> 6);  // row-quad idx 0..31
    const int lane  = threadIdx.x & 63;
    const float* __restrict__ xp = x + (size_t)plane * IN_H * IN_W;

    // h[k][j]: horizontally filtered value at input row 8q-1+k, output col 2*lane+j
    float h[10][2];
    #pragma unroll
    for (int k = 0; k < 10; ++k) {
        const int r = 8 * q - 1 + k;
        if (r < 0 || r >= IN_H) {            // wave-uniform (q uniform per wave)
            h[k][0] = 0.0f; h[k][1] = 0.0f;
            continue;
        }
        const float4 v = *(const float4*)(xp + (size_t)r * IN_W + 4 * lane);
        float prev = __shfl_up(v.w, 1);      // x[4l-1]
        float next = __shfl_down(v.x, 1);    // x[4l+4]
        if (lane == 0)  prev = 0.0f;         // left zero-pad
        if (lane == 63) next = 0.0f;         // right zero-pad
        h[k][0] = prev + 3.0f * v.x + 3.0f * v.y + v.z;
        h[k][1] = v.y + 3.0f * v.z + 3.0f * v.w + next;
    }

    // Vertical [1,3,3,1]; combined scale (1/8)*(1/8) = 1/64 applied once.
    const float s = 1.0f / 64.0f;
    float* __restrict__ yp =
        y + (size_t)plane * OUT_H * OUT_W + (size_t)(4 * q) * OUT_W;
    #pragma unroll
    for (int j = 0; j < 4; ++j) {
        const int b = 2 * j;
        float2 o;
        o.x = (h[b][0] + 3.0f * h[b + 1][0] + 3.0f * h[b + 2][0] + h[b + 3][0]) * s;
        o.y = (h[b][1] + 3.0f * h[b + 1][1] + 3.0f * h[b + 2][1] + h[b + 3][1]) * s;
        *(float2*)(yp + (size_t)j * OUT_W + 2 * lane) = o;
    }
}

extern "C" void kernel_launch(void* const* d_in, const int* in_sizes, int n_in,
                              void* d_out, int out_size, void* d_ws, size_t ws_size,
                              hipStream_t stream) {
    (void)n_in; (void)d_ws; (void)ws_size; (void)out_size;
    const float* x = (const float*)d_in[0];
    float* y = (float*)d_out;
    const int planes = in_sizes[0] / (IN_H * IN_W);   // B*C = 1024
    dim3 grid(8, planes);     // 8 blocks x 4 waves = 32 row-quads = 128 rows
    dim3 block(256);
    downsample_kernel<<<grid, block, 0, stream>>>(x, y);
}

// Round 5
// 58.885 us; speedup vs baseline: 3.3849x; 3.3849x over previous
//
#include <hip/hip_runtime.h>
#include <hip/hip_bf16.h>

// Depthwise 4x4 binomial blur + stride-2 downsample, separable [1,3,3,1] x2, /64.
// Input (B*C, 256, 256) fp32 -> output (B*C, 128, 128) fp32, pad=1.
//
// Barrier-free, LDS-free. One wave produces an output ROW-PAIR (rows 2p, 2p+1)
// from input rows 4p-1..4p+4. Each input row is one wave-wide float4 load
// (64 lanes x 16 B = whole 256-float row); horizontal [1,3,3,1] via 2 lane
// shuffles; vertical combine in registers. Edge rows handled BRANCHLESSLY
// (clamped row index + zero mask) so all 6 loads issue unconditionally
// back-to-back (no exec-mask regions, minimal live ranges).
// __launch_bounds__(256, 8) caps VGPR at 64 -> 8 waves/SIMD for latency hiding.

#define IN_H 256
#define IN_W 256
#define OUT_H 128
#define OUT_W 128

__global__ __launch_bounds__(256, 8) void downsample_kernel(
    const float* __restrict__ x, float* __restrict__ y) {
    const int plane = blockIdx.y;
    const int p     = blockIdx.x * 4 + (threadIdx.x >> 6);  // row-pair idx 0..63
    const int lane  = threadIdx.x & 63;
    const float* __restrict__ xp = x + (size_t)plane * IN_H * IN_W;

    // h[k][j]: horizontally filtered value at input row 4p-1+k, output col 2*lane+j
    float h[6][2];
    #pragma unroll
    for (int k = 0; k < 6; ++k) {
        const int r  = 4 * p - 1 + k;
        const int rc = min(max(r, 0), IN_H - 1);          // clamped (always in-bounds)
        const float m = (r == rc) ? 1.0f : 0.0f;          // zero-pad mask (top/bottom)
        const float4 v = *(const float4*)(xp + (size_t)rc * IN_W + 4 * lane);
        float prev = __shfl_up(v.w, 1);                   // x[4l-1]
        float next = __shfl_down(v.x, 1);                 // x[4l+4]
        prev = (lane == 0)  ? 0.0f : prev;                // left zero-pad
        next = (lane == 63) ? 0.0f : next;                // right zero-pad
        h[k][0] = m * (prev + 3.0f * v.x + 3.0f * v.y + v.z);
        h[k][1] = m * (v.y + 3.0f * v.z + 3.0f * v.w + next);
    }

    // Vertical [1,3,3,1]; combined scale (1/8)*(1/8) = 1/64 applied once.
    const float s = 1.0f / 64.0f;
    float2 o0, o1;
    o0.x = (h[0][0] + 3.0f * h[1][0] + 3.0f * h[2][0] + h[3][0]) * s;
    o0.y = (h[0][1] + 3.0f * h[1][1] + 3.0f * h[2][1] + h[3][1]) * s;
    o1.x = (h[2][0] + 3.0f * h[3][0] + 3.0f * h[4][0] + h[5][0]) * s;
    o1.y = (h[2][1] + 3.0f * h[3][1] + 3.0f * h[4][1] + h[5][1]) * s;

    float* __restrict__ yp =
        y + (size_t)plane * OUT_H * OUT_W + (size_t)(2 * p) * OUT_W;
    *(float2*)(yp + 2 * lane)         = o0;   // output row 2p
    *(float2*)(yp + OUT_W + 2 * lane) = o1;   // output row 2p+1
}

extern "C" void kernel_launch(void* const* d_in, const int* in_sizes, int n_in,
                              void* d_out, int out_size, void* d_ws, size_t ws_size,
                              hipStream_t stream) {
    (void)n_in; (void)d_ws; (void)ws_size; (void)out_size;
    const float* x = (const float*)d_in[0];
    float* y = (float*)d_out;
    const int planes = in_sizes[0] / (IN_H * IN_W);   // B*C = 1024
    dim3 grid(16, planes);    // 16 blocks x 4 waves = 64 row-pairs = 128 rows
    dim3 block(256);
    downsample_kernel<<<grid, block, 0, stream>>>(x, y);
}

// Round 6
// 53.693 us; speedup vs baseline: 3.7122x; 1.0967x over previous
//
#include <hip/hip_runtime.h>
#include <hip/hip_bf16.h>

// Depthwise 4x4 binomial blur + stride-2 downsample, separable [1,3,3,1] x2, /64.
// Input (B*C, 256, 256) fp32 -> output (B*C, 128, 128) fp32, pad=1.
//
// Barrier-free, LDS-free. One wave produces FOUR output rows (4q..4q+3) in two
// sequential phases with an h-carry, reading 10 input rows (8q-1..8q+8) total:
//   phase 1: load rows 8q-1..8q+4 (6x wave-wide float4), h0..h5, emit rows 4q,4q+1
//   phase 2: load rows 8q+5..8q+8 (4 loads), carry h4,h5, emit rows 4q+2,4q+3
// Issue-level read amplification 10/8 = 1.25x (vs 1.5x for row-pair waves).
// Edges branchless (clamped row + zero mask). Stores are NONTEMPORAL so the
// 67 MB of output writes don't evict the (L3-resident) input.
// __launch_bounds__(256, 8) caps VGPR at 64 -> 8 waves/SIMD.

#define IN_H 256
#define IN_W 256
#define OUT_H 128
#define OUT_W 128

__device__ __forceinline__ void hrow(const float* __restrict__ xp, int r,
                                     int lane, float& h0, float& h1) {
    const int rc  = min(max(r, 0), IN_H - 1);
    const float m = (r == rc) ? 1.0f : 0.0f;     // zero-pad mask (top/bottom)
    const float4 v = *(const float4*)(xp + (size_t)rc * IN_W + 4 * lane);
    float prev = __shfl_up(v.w, 1);              // x[4l-1]
    float next = __shfl_down(v.x, 1);            // x[4l+4]
    prev = (lane == 0)  ? 0.0f : prev;           // left zero-pad
    next = (lane == 63) ? 0.0f : next;           // right zero-pad
    h0 = m * (prev + 3.0f * v.x + 3.0f * v.y + v.z);
    h1 = m * (v.y + 3.0f * v.z + 3.0f * v.w + next);
}

__device__ __forceinline__ void nt_store2(float* p, float a, float b) {
    float2 o; o.x = a; o.y = b;
    __builtin_nontemporal_store(*(double*)&o, (double*)p);
}

__global__ __launch_bounds__(256, 8) void downsample_kernel(
    const float* __restrict__ x, float* __restrict__ y) {
    const int plane = blockIdx.y;
    const int q     = blockIdx.x * 4 + (threadIdx.x >> 6);  // row-quad idx 0..31
    const int lane  = threadIdx.x & 63;
    const float* __restrict__ xp = x + (size_t)plane * IN_H * IN_W;
    float* __restrict__ yp =
        y + (size_t)plane * OUT_H * OUT_W + (size_t)(4 * q) * OUT_W;
    const float s = 1.0f / 64.0f;   // (1/8)*(1/8) applied once

    // ---- Phase 1: rows 8q-1 .. 8q+4 -> output rows 4q, 4q+1 ----
    float h[6][2];
    #pragma unroll
    for (int k = 0; k < 6; ++k)
        hrow(xp, 8 * q - 1 + k, lane, h[k][0], h[k][1]);

    nt_store2(yp + 2 * lane,
              (h[0][0] + 3.0f * h[1][0] + 3.0f * h[2][0] + h[3][0]) * s,
              (h[0][1] + 3.0f * h[1][1] + 3.0f * h[2][1] + h[3][1]) * s);
    nt_store2(yp + OUT_W + 2 * lane,
              (h[2][0] + 3.0f * h[3][0] + 3.0f * h[4][0] + h[5][0]) * s,
              (h[2][1] + 3.0f * h[3][1] + 3.0f * h[4][1] + h[5][1]) * s);

    // ---- Phase 2: rows 8q+5 .. 8q+8, carry h[4],h[5] -> rows 4q+2, 4q+3 ----
    float g[4][2];
    #pragma unroll
    for (int k = 0; k < 4; ++k)
        hrow(xp, 8 * q + 5 + k, lane, g[k][0], g[k][1]);

    nt_store2(yp + 2 * OUT_W + 2 * lane,
              (h[4][0] + 3.0f * h[5][0] + 3.0f * g[0][0] + g[1][0]) * s,
              (h[4][1] + 3.0f * h[5][1] + 3.0f * g[0][1] + g[1][1]) * s);
    nt_store2(yp + 3 * OUT_W + 2 * lane,
              (g[0][0] + 3.0f * g[1][0] + 3.0f * g[2][0] + g[3][0]) * s,
              (g[0][1] + 3.0f * g[1][1] + 3.0f * g[2][1] + g[3][1]) * s);
}

extern "C" void kernel_launch(void* const* d_in, const int* in_sizes, int n_in,
                              void* d_out, int out_size, void* d_ws, size_t ws_size,
                              hipStream_t stream) {
    (void)n_in; (void)d_ws; (void)ws_size; (void)out_size;
    const float* x = (const float*)d_in[0];
    float* y = (float*)d_out;
    const int planes = in_sizes[0] / (IN_H * IN_W);   // B*C = 1024
    dim3 grid(8, planes);     // 8 blocks x 4 waves = 32 row-quads = 128 rows
    dim3 block(256);
    downsample_kernel<<<grid, block, 0, stream>>>(x, y);
}